// Round 6
// baseline (377.122 us; speedup 1.0000x reference)
//
#include <hip/hip_runtime.h>
#include <math.h>

#define DM 1024     // d_model
#define NH 16       // heads
#define HD 64       // head dim
#define SQ 2048     // seq
#define NB 4        // batch
#define MR (NB*SQ)  // 8192 rows

typedef unsigned short ushort_t;
typedef __attribute__((ext_vector_type(8)))  short bf16x8;
typedef __attribute__((ext_vector_type(4)))  float f32x4;
typedef __attribute__((ext_vector_type(16))) float f32x16;

__device__ __forceinline__ ushort_t f2bf(float f) {
    unsigned u = __float_as_uint(f);
    return (ushort_t)((u + 0x7fffu + ((u >> 16) & 1u)) >> 16);
}
__device__ __forceinline__ float bf2f(ushort_t u) {
    return __uint_as_float((unsigned)u << 16);
}

__device__ __forceinline__ void gload16(const void* g, void* l) {
    __builtin_amdgcn_global_load_lds(
        (const __attribute__((address_space(1))) void*)g,
        (__attribute__((address_space(3))) void*)l, 16, 0, 0);
}

// pack two f32 -> dword of 2x bf16 (low = a, high = b); no builtin on gfx950
__device__ __forceinline__ unsigned cvtpk_bf16(float a, float b) {
    unsigned r;
    asm volatile("v_cvt_pk_bf16_f32 %0, %1, %2" : "=v"(r) : "v"(a), "v"(b));
    return r;
}

// ---------------------------------------------------------------------------
__global__ __launch_bounds__(256)
void f2bf_kernel(const float* __restrict__ in, ushort_t* __restrict__ out) {
    int i = (blockIdx.x * 256 + threadIdx.x) * 4;
    float4 v = *reinterpret_cast<const float4*>(&in[i]);
    ushort4 o;
    o.x = f2bf(v.x); o.y = f2bf(v.y); o.z = f2bf(v.z); o.w = f2bf(v.w);
    *reinterpret_cast<ushort4*>(&out[i]) = o;
}

__global__ __launch_bounds__(256)
void w4_convert(const float* __restrict__ w0, const float* __restrict__ w1,
                const float* __restrict__ w2, const float* __restrict__ w3,
                ushort_t* __restrict__ out) {
    int i = (blockIdx.x * 256 + threadIdx.x) * 4;
    const int WSZ = DM * DM;
    const float* src = (i < WSZ) ? w0 : (i < 2 * WSZ) ? w1
                     : (i < 3 * WSZ) ? w2 : w3;
    int off = i & (WSZ - 1);
    float4 v = *reinterpret_cast<const float4*>(&src[off]);
    ushort4 o;
    o.x = f2bf(v.x); o.y = f2bf(v.y); o.z = f2bf(v.z); o.w = f2bf(v.w);
    *reinterpret_cast<ushort4*>(&out[i]) = o;
}

// ---------------------------------------------------------------------------
// bf16 MFMA GEMM (m97 structure), C = A @ B^T; MODE selects C layout:
// 0: fp32 flat [M][N]; 1: bf16 ((n*NH+h)*SQ+s)*HD+d (row->(n,s), col->(h,d));
// 2: bf16 ((n*NH+h)*HD+d)*SQ+s (row->(h,d), col->(n,s)) — V^T when A=W, B=x.
// ---------------------------------------------------------------------------
template<int MODE>
__global__ __launch_bounds__(256)
void gemm_bf16_bt(const ushort_t* __restrict__ A, const ushort_t* __restrict__ B,
                  void* __restrict__ Cv, int M, int N, int K, float scale)
{
    __shared__ ushort_t As[128 * 32];
    __shared__ ushort_t Bs[128 * 32];

    const int tid = threadIdx.x;
    const int w  = tid >> 6;
    const int l  = tid & 63;
    const int wr = w >> 1, wc = w & 1;
    const int arow0 = blockIdx.y * 128;
    const int bcol0 = blockIdx.x * 128;
    const int lr = l & 15;
    const int kg = l >> 4;

    const int srow[2] = { (w * 2 + 0) * 16 + (l >> 2), (w * 2 + 1) * 16 + (l >> 2) };
    const int scol = (l & 3) * 8;

    f32x4 acc[4][4] = {};

    for (int k0 = 0; k0 < K; k0 += 32) {
        #pragma unroll
        for (int q = 0; q < 2; ++q) {
            int chunk = w * 2 + q;
            gload16(&A[(size_t)(arow0 + srow[q]) * K + k0 + scol], &As[chunk * 512]);
            gload16(&B[(size_t)(bcol0 + srow[q]) * K + k0 + scol], &Bs[chunk * 512]);
        }
        __syncthreads();

        bf16x8 af[4], bfr[4];
        #pragma unroll
        for (int m = 0; m < 4; ++m)
            af[m] = *reinterpret_cast<const bf16x8*>(
                        &As[(wr * 64 + m * 16 + lr) * 32 + kg * 8]);
        #pragma unroll
        for (int nn = 0; nn < 4; ++nn)
            bfr[nn] = *reinterpret_cast<const bf16x8*>(
                        &Bs[(wc * 64 + nn * 16 + lr) * 32 + kg * 8]);

        #pragma unroll
        for (int m = 0; m < 4; ++m)
            #pragma unroll
            for (int nn = 0; nn < 4; ++nn)
                acc[m][nn] = __builtin_amdgcn_mfma_f32_16x16x32_bf16(
                    af[m], bfr[nn], acc[m][nn], 0, 0, 0);
        __syncthreads();
    }

    const int crow = kg * 4;
    #pragma unroll
    for (int m = 0; m < 4; ++m) {
        #pragma unroll
        for (int nn = 0; nn < 4; ++nn) {
            #pragma unroll
            for (int r = 0; r < 4; ++r) {
                int row = arow0 + wr * 64 + m * 16 + crow + r;
                int col = bcol0 + wc * 64 + nn * 16 + lr;
                float v = acc[m][nn][r] * scale;
                if (MODE == 0) {
                    ((float*)Cv)[(size_t)row * N + col] = v;
                } else if (MODE == 1) {
                    int nb = row >> 11, s = row & (SQ - 1);
                    int hh = col >> 6,  d = col & 63;
                    ((ushort_t*)Cv)[(((size_t)nb * NH + hh) * SQ + s) * HD + d] = f2bf(v);
                } else {
                    int hh = row >> 6,  d = row & 63;
                    int nb = col >> 11, s = col & (SQ - 1);
                    ((ushort_t*)Cv)[(((size_t)nb * NH + hh) * HD + d) * SQ + s] = f2bf(v);
                }
            }
        }
    }
}

// ---------------------------------------------------------------------------
__global__ __launch_bounds__(256)
void rope_bf16(ushort_t* __restrict__ Q, ushort_t* __restrict__ K,
               const int* __restrict__ pos)
{
    int t = blockIdx.x * 256 + threadIdx.x;
    int j  = t & 31;
    int s  = (t >> 5) & (SQ - 1);
    int nh = t >> 16;
    size_t base = ((size_t)nh * SQ + s) * HD + 2 * j;

    float p = (float)pos[s];
    float inv = exp2f(-0.41524101186072848f * (float)j);
    float sn, cs;
    sincosf(p * inv, &sn, &cs);

    ushort2 q2 = *reinterpret_cast<ushort2*>(&Q[base]);
    ushort2 k2 = *reinterpret_cast<ushort2*>(&K[base]);
    float qx = bf2f(q2.x), qy = bf2f(q2.y);
    float kx = bf2f(k2.x), ky = bf2f(k2.y);
    ushort2 qo, ko;
    qo.x = f2bf(qx * cs - qy * sn);  qo.y = f2bf(qx * sn + qy * cs);
    ko.x = f2bf(kx * cs - ky * sn);  ko.y = f2bf(kx * sn + ky * cs);
    *reinterpret_cast<ushort2*>(&Q[base]) = qo;
    *reinterpret_cast<ushort2*>(&K[base]) = ko;
}

// ---------------------------------------------------------------------------
// MFMA flash attention, swapped-QK^T (T12 structure), causal.
// P-fragment half-exchange done with __shfl_xor(.,32) — semantics
// unambiguous (replaces the permlane32_swap whose direction was uncertain).
// ---------------------------------------------------------------------------
__global__ __launch_bounds__(256)
void flash_mfma(const ushort_t* __restrict__ Q, const ushort_t* __restrict__ K,
                const ushort_t* __restrict__ Vt, ushort_t* __restrict__ O)
{
    __shared__ ushort_t Ks [64 * 64];   // [kv][d], XOR-swizzled 16B units
    __shared__ ushort_t Vts[64 * 64];   // [d][kv], XOR-swizzled 16B units

    const int tid  = threadIdx.x;
    const int wq   = tid >> 6;
    const int lane = tid & 63;
    const int q5   = lane & 31;
    const int g    = lane >> 5;
    const int qb   = blockIdx.x;
    const int h    = blockIdx.y;
    const int n    = blockIdx.z;

    const size_t hb = (size_t)(n * NH + h);
    const ushort_t* Kp  = K  + hb * SQ * HD;
    const ushort_t* Vtp = Vt + hb * HD * SQ;

    const int qglob = qb * 128 + wq * 32 + q5;
    const int qwave = qb * 128 + wq * 32;
    const int qmaxw = qwave + 31;
    const int nt    = 2 * qb + 2;       // kv tiles: cover 0 .. qb*128+127

    bf16x8 qf[4];
    {
        const ushort_t* Qr = Q + (hb * SQ + (size_t)qglob) * HD;
        #pragma unroll
        for (int s4 = 0; s4 < 4; ++s4)
            qf[s4] = *reinterpret_cast<const bf16x8*>(&Qr[s4 * 16 + g * 8]);
    }

    const int srowl = (lane >> 3);
    const int scole = ((lane & 7) ^ srowl) * 8;    // pre-swizzled source col

    f32x16 o0 = {}, o1 = {};
    float m_run = -1e30f, l_run = 0.f;

    for (int t = 0; t < nt; ++t) {
        const int kvbase = t * 64;

        __syncthreads();
        #pragma unroll
        for (int qi = 0; qi < 2; ++qi) {
            int c = wq * 2 + qi;
            int row = c * 8 + srowl;
            gload16(&Kp [(size_t)(kvbase + row) * HD + scole], &Ks [c * 512]);
            gload16(&Vtp[(size_t)row * SQ + kvbase + scole],   &Vts[c * 512]);
        }
        __syncthreads();

        if (kvbase <= qmaxw) {
            f32x16 st0 = {}, st1 = {};
            #pragma unroll
            for (int s4 = 0; s4 < 4; ++s4) {
                {   int row = q5;
                    int c16 = (s4 * 2 + g) ^ (row & 7);
                    bf16x8 kf = *reinterpret_cast<const bf16x8*>(&Ks[row * 64 + c16 * 8]);
                    st0 = __builtin_amdgcn_mfma_f32_32x32x16_bf16(kf, qf[s4], st0, 0, 0, 0);
                }
                {   int row = 32 + q5;
                    int c16 = (s4 * 2 + g) ^ (row & 7);
                    bf16x8 kf = *reinterpret_cast<const bf16x8*>(&Ks[row * 64 + c16 * 8]);
                    st1 = __builtin_amdgcn_mfma_f32_32x32x16_bf16(kf, qf[s4], st1, 0, 0, 0);
                }
            }

            if (kvbase + 63 > qwave) {
                #pragma unroll
                for (int r = 0; r < 16; ++r) {
                    int kvr = kvbase + (r & 3) + 8 * (r >> 2) + 4 * g;
                    if (kvr      > qglob) st0[r] = -1e30f;
                    if (kvr + 32 > qglob) st1[r] = -1e30f;
                }
            }

            float pmax = -1e30f;
            #pragma unroll
            for (int r = 0; r < 16; ++r) {
                pmax = fmaxf(pmax, st0[r]);
                pmax = fmaxf(pmax, st1[r]);
            }
            pmax = fmaxf(pmax, __shfl_xor(pmax, 32));
            float mnew = fmaxf(m_run, pmax);

            float rs = 0.f;
            #pragma unroll
            for (int r = 0; r < 16; ++r) {
                st0[r] = __expf(st0[r] - mnew); rs += st0[r];
                st1[r] = __expf(st1[r] - mnew); rs += st1[r];
            }
            rs += __shfl_xor(rs, 32);

            float sc = __expf(m_run - mnew);
            l_run = l_run * sc + rs;
            m_run = mnew;

            #pragma unroll
            for (int r = 0; r < 16; ++r) {
                float scb = __shfl(sc, (r & 3) + 8 * (r >> 2) + 4 * g, 64);
                o0[r] *= scb;
                o1[r] *= scb;
            }

            // P -> bf16 A-frags for PV.  Lane (q=q5, half g) needs, per
            // kv-slice s (kv = s*16 + g*8 + j, j=0..7):
            //   g=0: d0=wA0(own) d1=wA1(own) d2=partner's wA0 d3=partner's wA1
            //   g=1: d0=partner's wB0 d1=partner's wB1 d2=wB0(own) d3=wB1(own)
            // Exchange: each lane sends what its partner needs (g?wA:wB),
            // receives via unambiguous __shfl_xor lane^32.
            #pragma unroll
            for (int s = 0; s < 4; ++s) {
                const int bA = (s & 1) * 8;
                const int bB = bA + 4;
                float pa0, pa1, pa2, pa3, pb0, pb1, pb2, pb3;
                if (s < 2) {
                    pa0 = st0[bA]; pa1 = st0[bA+1]; pa2 = st0[bA+2]; pa3 = st0[bA+3];
                    pb0 = st0[bB]; pb1 = st0[bB+1]; pb2 = st0[bB+2]; pb3 = st0[bB+3];
                } else {
                    pa0 = st1[bA]; pa1 = st1[bA+1]; pa2 = st1[bA+2]; pa3 = st1[bA+3];
                    pb0 = st1[bB]; pb1 = st1[bB+1]; pb2 = st1[bB+2]; pb3 = st1[bB+3];
                }
                unsigned wA0 = cvtpk_bf16(pa0, pa1), wA1 = cvtpk_bf16(pa2, pa3);
                unsigned wB0 = cvtpk_bf16(pb0, pb1), wB1 = cvtpk_bf16(pb2, pb3);

                unsigned send0 = g ? wA0 : wB0;
                unsigned send1 = g ? wA1 : wB1;
                unsigned recv0 = (unsigned)__shfl_xor((int)send0, 32, 64);
                unsigned recv1 = (unsigned)__shfl_xor((int)send1, 32, 64);

                unsigned d0 = g ? recv0 : wA0;
                unsigned d1 = g ? recv1 : wA1;
                unsigned d2 = g ? wB0 : recv0;
                unsigned d3 = g ? wB1 : recv1;

                int4 pi = make_int4((int)d0, (int)d1, (int)d2, (int)d3);
                bf16x8 pa = *reinterpret_cast<bf16x8*>(&pi);

                {   int row = q5;
                    int c16 = (s * 2 + g) ^ (row & 7);
                    bf16x8 vf = *reinterpret_cast<const bf16x8*>(&Vts[row * 64 + c16 * 8]);
                    o0 = __builtin_amdgcn_mfma_f32_32x32x16_bf16(pa, vf, o0, 0, 0, 0);
                }
                {   int row = 32 + q5;
                    int c16 = (s * 2 + g) ^ (row & 7);
                    bf16x8 vf = *reinterpret_cast<const bf16x8*>(&Vts[row * 64 + c16 * 8]);
                    o1 = __builtin_amdgcn_mfma_f32_32x32x16_bf16(pa, vf, o1, 0, 0, 0);
                }
            }
        }
    }

    float linv = 1.0f / l_run;
    #pragma unroll
    for (int r = 0; r < 16; ++r) {
        int qr = (r & 3) + 8 * (r >> 2) + 4 * g;
        float lb = __shfl(linv, qr, 64);
        size_t rowb = ((size_t)n * SQ + qb * 128 + wq * 32 + qr) * DM + h * 64;
        O[rowb + q5]      = f2bf(o0[r] * lb);
        O[rowb + 32 + q5] = f2bf(o1[r] * lb);
    }
}

// ---------------------------------------------------------------------------
extern "C" void kernel_launch(void* const* d_in, const int* in_sizes, int n_in,
                              void* d_out, int out_size, void* d_ws, size_t ws_size,
                              hipStream_t stream)
{
    const float* x   = (const float*)d_in[0];
    const int*   pos = (const int*)  d_in[1];
    const float* W_Q = (const float*)d_in[2];
    const float* W_K = (const float*)d_in[3];
    const float* W_V = (const float*)d_in[4];
    const float* W_O = (const float*)d_in[5];
    float* out = (float*)d_out;

    const size_t T   = (size_t)NB * SQ * DM;
    const size_t WSZ = (size_t)DM * DM;

    ushort_t* xb  = (ushort_t*)d_ws;
    ushort_t* Wb  = xb + T;
    ushort_t* Qb  = Wb + 4 * WSZ;
    ushort_t* Kb  = Qb + T;
    ushort_t* Vtb = Kb + T;
    ushort_t* Op  = xb;                     // alias: xb dead after V-GEMM

    const ushort_t* WQb = Wb;
    const ushort_t* WKb = Wb + WSZ;
    const ushort_t* WVb = Wb + 2 * WSZ;
    const ushort_t* WOb = Wb + 3 * WSZ;

    f2bf_kernel<<<T / 1024, 256, 0, stream>>>(x, xb);
    w4_convert<<<4 * WSZ / 1024, 256, 0, stream>>>(W_Q, W_K, W_V, W_O, Wb);

    dim3 gQK(DM / 128, MR / 128);
    gemm_bf16_bt<1><<<gQK, 256, 0, stream>>>(xb, WQb, Qb, MR, DM, DM, 0.125f);
    gemm_bf16_bt<1><<<gQK, 256, 0, stream>>>(xb, WKb, Kb, MR, DM, DM, 1.0f);
    dim3 gV(MR / 128, DM / 128);
    gemm_bf16_bt<2><<<gV, 256, 0, stream>>>(WVb, xb, Vtb, DM, MR, DM, 1.0f);

    rope_bf16<<<(NB * NH * SQ * 32) / 256, 256, 0, stream>>>(Qb, Kb, pos);

    dim3 agrid(SQ / 128, NH, NB);
    flash_mfma<<<agrid, 256, 0, stream>>>(Qb, Kb, Vtb, Op);

    dim3 gO(DM / 128, MR / 128);
    gemm_bf16_bt<0><<<gO, 256, 0, stream>>>(Op, WOb, out, MR, DM, DM, 1.0f);
}

// Round 8
// 354.386 us; speedup vs baseline: 1.0642x; 1.0642x over previous
//
#include <hip/hip_runtime.h>
#include <math.h>

#define DM 1024     // d_model
#define NH 16       // heads
#define HD 64       // head dim
#define SQ 2048     // seq
#define NB 4        // batch
#define MR (NB*SQ)  // 8192 rows
#define TTOT ((size_t)MR * DM)   // 8388608 elements per activation tensor

typedef unsigned short ushort_t;
typedef __attribute__((ext_vector_type(8)))  short bf16x8;
typedef __attribute__((ext_vector_type(4)))  float f32x4;
typedef __attribute__((ext_vector_type(16))) float f32x16;

__device__ __forceinline__ ushort_t f2bf(float f) {
    unsigned u = __float_as_uint(f);
    return (ushort_t)((u + 0x7fffu + ((u >> 16) & 1u)) >> 16);
}
__device__ __forceinline__ float bf2f(ushort_t u) {
    return __uint_as_float((unsigned)u << 16);
}

__device__ __forceinline__ void gload16(const void* g, void* l) {
    __builtin_amdgcn_global_load_lds(
        (const __attribute__((address_space(1))) void*)g,
        (__attribute__((address_space(3))) void*)l, 16, 0, 0);
}

// pack two f32 -> dword of 2x bf16 (low = a, high = b); no builtin on gfx950
__device__ __forceinline__ unsigned cvtpk_bf16(float a, float b) {
    unsigned r;
    asm volatile("v_cvt_pk_bf16_f32 %0, %1, %2" : "=v"(r) : "v"(a), "v"(b));
    return r;
}

// ---------------------------------------------------------------------------
__global__ __launch_bounds__(256)
void f2bf_kernel(const float* __restrict__ in, ushort_t* __restrict__ out) {
    int i = (blockIdx.x * 256 + threadIdx.x) * 4;
    float4 v = *reinterpret_cast<const float4*>(&in[i]);
    ushort4 o;
    o.x = f2bf(v.x); o.y = f2bf(v.y); o.z = f2bf(v.z); o.w = f2bf(v.w);
    *reinterpret_cast<ushort4*>(&out[i]) = o;
}

__global__ __launch_bounds__(256)
void w4_convert(const float* __restrict__ w0, const float* __restrict__ w1,
                const float* __restrict__ w2, const float* __restrict__ w3,
                ushort_t* __restrict__ out) {
    int i = (blockIdx.x * 256 + threadIdx.x) * 4;
    const int WSZ = DM * DM;
    const float* src = (i < WSZ) ? w0 : (i < 2 * WSZ) ? w1
                     : (i < 3 * WSZ) ? w2 : w3;
    int off = i & (WSZ - 1);
    float4 v = *reinterpret_cast<const float4*>(&src[off]);
    ushort4 o;
    o.x = f2bf(v.x); o.y = f2bf(v.y); o.z = f2bf(v.z); o.w = f2bf(v.w);
    *reinterpret_cast<ushort4*>(&out[i]) = o;
}

// ---------------------------------------------------------------------------
// bf16 MFMA GEMM (m97 structure), C = A @ B^T; MODE selects C layout:
// 0: fp32 flat [M][N]
// 2: bf16 ((n*NH+h)*HD+d)*SQ+s (row->(h,d), col->(n,s)) — V^T when A=W, B=x
// 3: fused Q+K: col<1024 -> Q (scale 0.125), col>=1024 -> K (at Cv + TTOT);
//    both written bf16 ((n*NH+h)*SQ+s)*HD+d
// ---------------------------------------------------------------------------
template<int MODE>
__global__ __launch_bounds__(256)
void gemm_bf16_bt(const ushort_t* __restrict__ A, const ushort_t* __restrict__ B,
                  void* __restrict__ Cv, int M, int N, int K, float scale)
{
    __shared__ ushort_t As[128 * 32];
    __shared__ ushort_t Bs[128 * 32];

    const int tid = threadIdx.x;
    const int w  = tid >> 6;
    const int l  = tid & 63;
    const int wr = w >> 1, wc = w & 1;
    const int arow0 = blockIdx.y * 128;
    const int bcol0 = blockIdx.x * 128;
    const int lr = l & 15;
    const int kg = l >> 4;

    const int srow[2] = { (w * 2 + 0) * 16 + (l >> 2), (w * 2 + 1) * 16 + (l >> 2) };
    const int scol = (l & 3) * 8;

    f32x4 acc[4][4] = {};

    for (int k0 = 0; k0 < K; k0 += 32) {
        #pragma unroll
        for (int q = 0; q < 2; ++q) {
            int chunk = w * 2 + q;
            gload16(&A[(size_t)(arow0 + srow[q]) * K + k0 + scol], &As[chunk * 512]);
            gload16(&B[(size_t)(bcol0 + srow[q]) * K + k0 + scol], &Bs[chunk * 512]);
        }
        __syncthreads();

        bf16x8 af[4], bfr[4];
        #pragma unroll
        for (int m = 0; m < 4; ++m)
            af[m] = *reinterpret_cast<const bf16x8*>(
                        &As[(wr * 64 + m * 16 + lr) * 32 + kg * 8]);
        #pragma unroll
        for (int nn = 0; nn < 4; ++nn)
            bfr[nn] = *reinterpret_cast<const bf16x8*>(
                        &Bs[(wc * 64 + nn * 16 + lr) * 32 + kg * 8]);

        #pragma unroll
        for (int m = 0; m < 4; ++m)
            #pragma unroll
            for (int nn = 0; nn < 4; ++nn)
                acc[m][nn] = __builtin_amdgcn_mfma_f32_16x16x32_bf16(
                    af[m], bfr[nn], acc[m][nn], 0, 0, 0);
        __syncthreads();
    }

    const int crow = kg * 4;
    #pragma unroll
    for (int m = 0; m < 4; ++m) {
        #pragma unroll
        for (int nn = 0; nn < 4; ++nn) {
            #pragma unroll
            for (int r = 0; r < 4; ++r) {
                int row = arow0 + wr * 64 + m * 16 + crow + r;
                int col = bcol0 + wc * 64 + nn * 16 + lr;
                float v = acc[m][nn][r] * scale;
                if (MODE == 0) {
                    ((float*)Cv)[(size_t)row * N + col] = v;
                } else if (MODE == 2) {
                    int hh = row >> 6,  d = row & 63;
                    int nb = col >> 11, s = col & (SQ - 1);
                    ((ushort_t*)Cv)[(((size_t)nb * NH + hh) * HD + d) * SQ + s] = f2bf(v);
                } else {   // MODE 3: fused Q+K
                    int nb = row >> 11, s = row & (SQ - 1);
                    bool isq = (col < 1024);
                    int cc = col & 1023;
                    int hh = cc >> 6, d = cc & 63;
                    size_t idx = (((size_t)nb * NH + hh) * SQ + s) * HD + d;
                    float vv = isq ? v * 0.125f : v;
                    ((ushort_t*)Cv)[(isq ? (size_t)0 : TTOT) + idx] = f2bf(vv);
                }
            }
        }
    }
}

// ---------------------------------------------------------------------------
__global__ __launch_bounds__(256)
void rope_bf16(ushort_t* __restrict__ Q, ushort_t* __restrict__ K,
               const int* __restrict__ pos)
{
    int t = blockIdx.x * 256 + threadIdx.x;
    int j  = t & 31;
    int s  = (t >> 5) & (SQ - 1);
    int nh = t >> 16;
    size_t base = ((size_t)nh * SQ + s) * HD + 2 * j;

    float p = (float)pos[s];
    float inv = exp2f(-0.41524101186072848f * (float)j);
    float sn, cs;
    sincosf(p * inv, &sn, &cs);

    ushort2 q2 = *reinterpret_cast<ushort2*>(&Q[base]);
    ushort2 k2 = *reinterpret_cast<ushort2*>(&K[base]);
    float qx = bf2f(q2.x), qy = bf2f(q2.y);
    float kx = bf2f(k2.x), ky = bf2f(k2.y);
    ushort2 qo, ko;
    qo.x = f2bf(qx * cs - qy * sn);  qo.y = f2bf(qx * sn + qy * cs);
    ko.x = f2bf(kx * cs - ky * sn);  ko.y = f2bf(kx * sn + ky * cs);
    *reinterpret_cast<ushort2*>(&Q[base]) = qo;
    *reinterpret_cast<ushort2*>(&K[base]) = ko;
}

// ---------------------------------------------------------------------------
// MFMA flash attention, swapped-QK^T, causal.
// R6 counters showed latency-bound (MfmaUtil 8.8%, 60% idle): this version
// adds (a) double-buffered K/V LDS with prefetch-next-tile + ONE barrier per
// tile (load latency hides under compute), (b) defer-max rescale skip
// (T13, THR=8) removing the 32-bpermute rescale on almost every tile,
// (c) LPT block order (qb descending) for the causal skew.
// ---------------------------------------------------------------------------
__global__ __launch_bounds__(256)
void flash_mfma(const ushort_t* __restrict__ Q, const ushort_t* __restrict__ K,
                const ushort_t* __restrict__ Vt, ushort_t* __restrict__ O)
{
    __shared__ ushort_t Ks [2][64 * 64];   // [buf][kv][d], XOR-swizzled 16B units
    __shared__ ushort_t Vts[2][64 * 64];   // [buf][d][kv], XOR-swizzled 16B units

    const int tid  = threadIdx.x;
    const int wq   = tid >> 6;
    const int lane = tid & 63;
    const int q5   = lane & 31;
    const int g    = lane >> 5;
    const int qb   = (gridDim.x - 1) - blockIdx.x;   // LPT: big blocks first
    const int h    = blockIdx.y;
    const int n    = blockIdx.z;

    const size_t hb = (size_t)(n * NH + h);
    const ushort_t* Kp  = K  + hb * SQ * HD;
    const ushort_t* Vtp = Vt + hb * HD * SQ;

    const int qglob = qb * 128 + wq * 32 + q5;
    const int qwave = qb * 128 + wq * 32;
    const int qmaxw = qwave + 31;
    const int nt    = 2 * qb + 2;       // kv tiles: cover 0 .. qb*128+127

    bf16x8 qf[4];
    {
        const ushort_t* Qr = Q + (hb * SQ + (size_t)qglob) * HD;
        #pragma unroll
        for (int s4 = 0; s4 < 4; ++s4)
            qf[s4] = *reinterpret_cast<const bf16x8*>(&Qr[s4 * 16 + g * 8]);
    }

    const int srowl = (lane >> 3);
    const int scole = ((lane & 7) ^ srowl) * 8;    // pre-swizzled source col

    auto stage = [&](int buf, int t) {
        const int kvb = t * 64;
        #pragma unroll
        for (int qi = 0; qi < 2; ++qi) {
            int c = wq * 2 + qi;
            int row = c * 8 + srowl;
            gload16(&Kp [(size_t)(kvb + row) * HD + scole], &Ks [buf][c * 512]);
            gload16(&Vtp[(size_t)row * SQ + kvb + scole],   &Vts[buf][c * 512]);
        }
    };

    f32x16 o0 = {}, o1 = {};
    float m_run = -1e30f, l_run = 0.f;

    stage(0, 0);
    __syncthreads();   // tile 0 staged

    for (int t = 0; t < nt; ++t) {
        const int cur = t & 1;
        const int kvbase = t * 64;

        if (t + 1 < nt) stage(cur ^ 1, t + 1);   // prefetch overlaps compute

        if (kvbase <= qmaxw) {
            f32x16 st0 = {}, st1 = {};
            #pragma unroll
            for (int s4 = 0; s4 < 4; ++s4) {
                {   int row = q5;
                    int c16 = (s4 * 2 + g) ^ (row & 7);
                    bf16x8 kf = *reinterpret_cast<const bf16x8*>(&Ks[cur][row * 64 + c16 * 8]);
                    st0 = __builtin_amdgcn_mfma_f32_32x32x16_bf16(kf, qf[s4], st0, 0, 0, 0);
                }
                {   int row = 32 + q5;
                    int c16 = (s4 * 2 + g) ^ (row & 7);
                    bf16x8 kf = *reinterpret_cast<const bf16x8*>(&Ks[cur][row * 64 + c16 * 8]);
                    st1 = __builtin_amdgcn_mfma_f32_32x32x16_bf16(kf, qf[s4], st1, 0, 0, 0);
                }
            }

            if (kvbase + 63 > qwave) {
                #pragma unroll
                for (int r = 0; r < 16; ++r) {
                    int kvr = kvbase + (r & 3) + 8 * (r >> 2) + 4 * g;
                    if (kvr      > qglob) st0[r] = -1e30f;
                    if (kvr + 32 > qglob) st1[r] = -1e30f;
                }
            }

            float pmax = -1e30f;
            #pragma unroll
            for (int r = 0; r < 16; ++r) {
                pmax = fmaxf(pmax, st0[r]);
                pmax = fmaxf(pmax, st1[r]);
            }
            pmax = fmaxf(pmax, __shfl_xor(pmax, 32));

            // defer-max (T13): skip rescale when max growth <= 8
            if (!__all(pmax - m_run <= 8.0f)) {
                float mnew = fmaxf(m_run, pmax);
                float sc = __expf(m_run - mnew);
                l_run *= sc;
                #pragma unroll
                for (int r = 0; r < 16; ++r) {
                    float scb = __shfl(sc, (r & 3) + 8 * (r >> 2) + 4 * g, 64);
                    o0[r] *= scb;
                    o1[r] *= scb;
                }
                m_run = mnew;
            }

            float rs = 0.f;
            #pragma unroll
            for (int r = 0; r < 16; ++r) {
                st0[r] = __expf(st0[r] - m_run); rs += st0[r];
                st1[r] = __expf(st1[r] - m_run); rs += st1[r];
            }
            rs += __shfl_xor(rs, 32);
            l_run += rs;

            // P -> bf16 A-frags for PV (unambiguous shfl_xor exchange)
            #pragma unroll
            for (int s = 0; s < 4; ++s) {
                const int bA = (s & 1) * 8;
                const int bB = bA + 4;
                float pa0, pa1, pa2, pa3, pb0, pb1, pb2, pb3;
                if (s < 2) {
                    pa0 = st0[bA]; pa1 = st0[bA+1]; pa2 = st0[bA+2]; pa3 = st0[bA+3];
                    pb0 = st0[bB]; pb1 = st0[bB+1]; pb2 = st0[bB+2]; pb3 = st0[bB+3];
                } else {
                    pa0 = st1[bA]; pa1 = st1[bA+1]; pa2 = st1[bA+2]; pa3 = st1[bA+3];
                    pb0 = st1[bB]; pb1 = st1[bB+1]; pb2 = st1[bB+2]; pb3 = st1[bB+3];
                }
                unsigned wA0 = cvtpk_bf16(pa0, pa1), wA1 = cvtpk_bf16(pa2, pa3);
                unsigned wB0 = cvtpk_bf16(pb0, pb1), wB1 = cvtpk_bf16(pb2, pb3);

                unsigned send0 = g ? wA0 : wB0;
                unsigned send1 = g ? wA1 : wB1;
                unsigned recv0 = (unsigned)__shfl_xor((int)send0, 32, 64);
                unsigned recv1 = (unsigned)__shfl_xor((int)send1, 32, 64);

                unsigned d0 = g ? recv0 : wA0;
                unsigned d1 = g ? recv1 : wA1;
                unsigned d2 = g ? wB0 : recv0;
                unsigned d3 = g ? wB1 : recv1;

                int4 pi = make_int4((int)d0, (int)d1, (int)d2, (int)d3);
                bf16x8 pa = *reinterpret_cast<bf16x8*>(&pi);

                {   int row = q5;
                    int c16 = (s * 2 + g) ^ (row & 7);
                    bf16x8 vf = *reinterpret_cast<const bf16x8*>(&Vts[cur][row * 64 + c16 * 8]);
                    o0 = __builtin_amdgcn_mfma_f32_32x32x16_bf16(pa, vf, o0, 0, 0, 0);
                }
                {   int row = 32 + q5;
                    int c16 = (s * 2 + g) ^ (row & 7);
                    bf16x8 vf = *reinterpret_cast<const bf16x8*>(&Vts[cur][row * 64 + c16 * 8]);
                    o1 = __builtin_amdgcn_mfma_f32_32x32x16_bf16(pa, vf, o1, 0, 0, 0);
                }
            }
        }

        __syncthreads();   // drains prefetch vmcnt; next tile ready & prev safe
    }

    float linv = 1.0f / l_run;
    #pragma unroll
    for (int r = 0; r < 16; ++r) {
        int qr = (r & 3) + 8 * (r >> 2) + 4 * g;
        float lb = __shfl(linv, qr, 64);
        size_t rowb = ((size_t)n * SQ + qb * 128 + wq * 32 + qr) * DM + h * 64;
        O[rowb + q5]      = f2bf(o0[r] * lb);
        O[rowb + 32 + q5] = f2bf(o1[r] * lb);
    }
}

// ---------------------------------------------------------------------------
extern "C" void kernel_launch(void* const* d_in, const int* in_sizes, int n_in,
                              void* d_out, int out_size, void* d_ws, size_t ws_size,
                              hipStream_t stream)
{
    const float* x   = (const float*)d_in[0];
    const int*   pos = (const int*)  d_in[1];
    const float* W_Q = (const float*)d_in[2];
    const float* W_K = (const float*)d_in[3];
    const float* W_V = (const float*)d_in[4];
    const float* W_O = (const float*)d_in[5];
    float* out = (float*)d_out;

    const size_t T   = TTOT;
    const size_t WSZ = (size_t)DM * DM;

    ushort_t* xb  = (ushort_t*)d_ws;
    ushort_t* Wb  = xb + T;
    ushort_t* Qb  = Wb + 4 * WSZ;
    ushort_t* Kb  = Qb + T;      // MUST stay Qb + T (fused QK epilogue)
    ushort_t* Vtb = Kb + T;
    ushort_t* Op  = xb;          // alias: xb dead after V-GEMM

    const ushort_t* WVb = Wb + 2 * WSZ;
    const ushort_t* WOb = Wb + 3 * WSZ;

    f2bf_kernel<<<T / 1024, 256, 0, stream>>>(x, xb);
    w4_convert<<<4 * WSZ / 1024, 256, 0, stream>>>(W_Q, W_K, W_V, W_O, Wb);

    // fused Q+K projection: B = [W_Q ; W_K] rows 0..2047 of Wb
    dim3 gQK(2048 / 128, MR / 128);             // 16 x 64
    gemm_bf16_bt<3><<<gQK, 256, 0, stream>>>(xb, Wb, Qb, MR, 2048, DM, 1.0f);
    // V^T: A = W_V, B = x
    dim3 gV(MR / 128, DM / 128);                // 64 x 8
    gemm_bf16_bt<2><<<gV, 256, 0, stream>>>(WVb, xb, Vtb, DM, MR, DM, 1.0f);

    rope_bf16<<<(NB * NH * SQ * 32) / 256, 256, 0, stream>>>(Qb, Kb, pos);

    dim3 agrid(SQ / 128, NH, NB);               // (16, 16, 4)
    flash_mfma<<<agrid, 256, 0, stream>>>(Qb, Kb, Vtb, Op);

    dim3 gO(DM / 128, MR / 128);
    gemm_bf16_bt<0><<<gO, 256, 0, stream>>>(Op, WOb, out, MR, DM, DM, 1.0f);
}